// Round 2
// baseline (12742.873 us; speedup 1.0000x reference)
//
#include <hip/hip_runtime.h>

#define BB 4
#define NN 16384
#define SS 4096
#define KK 16
#define KE 17                 // extended f32 list to expose boundary ties
#define PP 64
#define QQ 128

// flat FLOAT32 element offsets in d_out (return order: shapes, xyz_new, idx)
#define OFF_XYZNEW 2097152u   // 4*128*4096
#define OFF_IDX    2146304u   // + 4*4096*3
#define OUT_ELEMS  2408448u   // + 4*4096*16

// FPS: 512 threads (8 waves), 2 waves/SIMD -> 256-VGPR budget.
#define FTH 512
#define FPT (NN / FTH)        // 32
#define NWAVE (FTH / 64)      // 8

// KNN: 64 threads = 1 wave per block, 256 blocks -> all 256 CUs.
#define KTH 64
#define NBLK (SS / KTH)       // 64 blocks per batch
#define CAP 32                // per-lane LDS stack capacity
#define MARGIN 1e-3f          // >> worst-case |d32-d64| (~4e-5): f64 coverage proof

__device__ __forceinline__ float mulrn(float a, float b) { return __fmul_rn(a, b); }
__device__ __forceinline__ float addrn(float a, float b) { return __fadd_rn(a, b); }
__device__ __forceinline__ float subrn(float a, float b) { return __fsub_rn(a, b); }

// ---------------------------------------------------------------------------
// Kernel 1: farthest point sampling, 1 block per batch.
// v3: register-resident point coords.
//   - __launch_bounds__(512,2): 2 waves/SIMD -> 256 VGPR cap, so the
//     128 data registers (px/py/pz/dist) fit.
//   - asm "+v" pins after the init loads defeat load-rematerialization
//     (round-1 counters: VGPR_Count=84 < 128 array floats, fps FETCH 409MB
//     -> compiler was re-streaming coords from L1/L2 every iteration).
//   - winner coords ride the reduction as payload (shuffle + LDS), removing
//     the dependent global reload of base[bg*3] from the serial path.
// Selection key is strictly (v desc, g asc) everywhere -> sequence identical.
// ---------------------------------------------------------------------------
__global__ __launch_bounds__(FTH, 2) void fps_kernel(
    const float* __restrict__ xyz,
    float* __restrict__ out,
    float* __restrict__ ws, unsigned ws_floats)
{
    const int b   = blockIdx.x;
    const int tid = threadIdx.x;
    const float* base = xyz + (size_t)b * NN * 3;

    float px[FPT], py[FPT], pz[FPT], dist[FPT];
#pragma unroll
    for (int j = 0; j < FPT; ++j) {
        int g = tid + FTH * j;
        px[j] = base[g * 3 + 0];
        py[j] = base[g * 3 + 1];
        pz[j] = base[g * 3 + 2];
        dist[j] = 1e10f;
        // pin to VGPRs: value becomes opaque -> no remat-from-global
        asm volatile("" : "+v"(px[j]));
        asm volatile("" : "+v"(py[j]));
        asm volatile("" : "+v"(pz[j]));
    }

    __shared__ float wv[2][NWAVE];
    __shared__ int   wg[2][NWAVE];
    __shared__ float wx[2][NWAVE], wy[2][NWAVE], wz[2][NWAVE];

    // selection 0 is index 0
    float lx = base[0], ly = base[1], lz = base[2];
    if (tid == 0) {
        unsigned o = OFF_XYZNEW + (unsigned)b * SS * 3u;
        out[o + 0] = lx; out[o + 1] = ly; out[o + 2] = lz;
        unsigned w = (unsigned)b * SS * 3u;
        if (w + 2u < ws_floats) { ws[w] = lx; ws[w + 1] = ly; ws[w + 2] = lz; }
    }

    const int lane = tid & 63;
    const int wave = tid >> 6;
    int p = 0;

    for (int s = 1; s < SS; ++s) {
        float bestv = -1.0f;
        int   bestg = 0;
        float bx = 0.0f, by = 0.0f, bz = 0.0f;
#pragma unroll
        for (int j = 0; j < FPT; ++j) {
            float dx = subrn(px[j], lx);
            float dy = subrn(py[j], ly);
            float dz = subrn(pz[j], lz);
            float d  = addrn(addrn(mulrn(dx, dx), mulrn(dy, dy)), mulrn(dz, dz));
            float nd = fminf(dist[j], d);
            dist[j] = nd;
            if (nd > bestv) { bestv = nd; bestg = tid + FTH * j;
                              bx = px[j]; by = py[j]; bz = pz[j]; }
        }
        for (int off = 32; off >= 1; off >>= 1) {
            float ov = __shfl_down(bestv, off);
            int   og = __shfl_down(bestg, off);
            float ox = __shfl_down(bx, off);
            float oy = __shfl_down(by, off);
            float oz = __shfl_down(bz, off);
            if (ov > bestv || (ov == bestv && og < bestg)) {
                bestv = ov; bestg = og; bx = ox; by = oy; bz = oz;
            }
        }
        if (lane == 0) {
            wv[p][wave] = bestv; wg[p][wave] = bestg;
            wx[p][wave] = bx; wy[p][wave] = by; wz[p][wave] = bz;
        }
        __syncthreads();
        // single barrier: buffer p reads below are ordered before any write to
        // buffer p^1 (next iter) by this barrier; buffer p is only rewritten
        // two iterations later, after the next barrier.

        float bv = wv[p][0]; int bg = wg[p][0];
        lx = wx[p][0]; ly = wy[p][0]; lz = wz[p][0];
#pragma unroll
        for (int w = 1; w < NWAVE; ++w) {
            float v = wv[p][w]; int g = wg[p][w];
            if (v > bv || (v == bv && g < bg)) {
                bv = v; bg = g;
                lx = wx[p][w]; ly = wy[p][w]; lz = wz[p][w];
            }
        }

        if (tid == 0) {
            unsigned o = OFF_XYZNEW + ((unsigned)b * SS + (unsigned)s) * 3u;
            out[o + 0] = lx; out[o + 1] = ly; out[o + 2] = lz;
            unsigned w = ((unsigned)b * SS + (unsigned)s) * 3u;
            if (w + 2u < ws_floats) { ws[w] = lx; ws[w + 1] = ly; ws[w + 2] = lz; }
        }
        p ^= 1;
    }
}

// ---------------------------------------------------------------------------
// Kernel 2 (v3, unchanged from round 1): push/drain top-k.
// Hot loop: f32 distance (bit-identical r7 chain) + push (d,g) to per-lane
// LDS stack if d < tau+MARGIN (tau = kd[16] at last drain, stale-high).
// Drain (in scan order) replays EXACT original logic per entry:
//   - strict d < kd[16] f32 bubble insert (literal sequential replay: push
//     condition is a superset of the insert condition)
//   - recompute d64 from reloaded coords (identical f64 chain -> bit-identical)
//     and strict f64 insert. f64-top-16 members have d32 <= kd16_final + 2eps
//     (eps <= ~4e-5 for |values|<=~100), MARGIN=1e-3 guarantees they are
//     pushed; transient f64-list members cannot change the final 16.
// Emit rule, planes, shapes: unchanged.
// ---------------------------------------------------------------------------
__global__ __launch_bounds__(KTH) void knn_shape_kernel(
    const float* __restrict__ xyz,
    const float* __restrict__ ws, int use_ws, unsigned ws_floats,
    const float* __restrict__ w_planes, const float* __restrict__ w_shapes,
    const float* __restrict__ bn_gamma, const float* __restrict__ bn_beta,
    const float* __restrict__ bn_mean, const float* __restrict__ bn_var,
    float* __restrict__ out)
{
    __shared__ float sd[CAP][KTH];   // [cnt][lane]: bank = lane%32, conflict-free
    __shared__ int   sg[CAP][KTH];
    __shared__ float wpx[PP], wpy[PP], wpz[PP];
    __shared__ float wsh[QQ * PP];
    __shared__ float bsc[QQ], bmn[QQ], bbt[QQ];

    const int tid = threadIdx.x;
    const int blk = blockIdx.x;
    const int b   = blk / NBLK;
    const int s   = (blk % NBLK) * KTH + tid;   // [0, 4096)

    for (int i = tid; i < PP; i += KTH) {
        wpx[i] = w_planes[i * 3 + 0];
        wpy[i] = w_planes[i * 3 + 1];
        wpz[i] = w_planes[i * 3 + 2];
    }
    for (int i = tid; i < QQ * PP; i += KTH) wsh[i] = w_shapes[i];
    for (int i = tid; i < QQ; i += KTH) {
        bsc[i] = bn_gamma[i] / sqrtf(bn_var[i] + 1e-5f);
        bmn[i] = bn_mean[i];
        bbt[i] = bn_beta[i];
    }
    __syncthreads();

    const float* bx = xyz + (size_t)b * NN * 3;

    float qx, qy, qz;
    {
        unsigned w = ((unsigned)b * SS + (unsigned)s) * 3u;
        if (use_ws && w + 2u < ws_floats) {
            qx = ws[w]; qy = ws[w + 1]; qz = ws[w + 2];
        } else {
            unsigned o = OFF_XYZNEW + w;
            qx = out[o + 0]; qy = out[o + 1]; qz = out[o + 2];
        }
    }
    const float  qsq   = addrn(addrn(mulrn(qx, qx), mulrn(qy, qy)), mulrn(qz, qz));
    const double qxd = (double)qx, qyd = (double)qy, qzd = (double)qz;
    const double qsq64 = qxd * qxd + qyd * qyd + qzd * qzd;

    float  kd[KE];   int ki[KE];
    double kd64[KK]; int ki64[KK];
#pragma unroll
    for (int t = 0; t < KE; ++t) { kd[t] = 3.0e38f; ki[t] = 0; }
#pragma unroll
    for (int t = 0; t < KK; ++t) { kd64[t] = 1.0e300; ki64[t] = 0; }

    int   cnt  = 0;
    float taum = 3.0e38f;

    auto drain = [&]() {
        for (int t = 0; t < CAP; ++t) {
            if (!__any(t < cnt)) break;
            const bool act = t < cnt;
            float d = 0.0f; int g = 0;
            if (act) { d = sd[t][tid]; g = sg[t][tid]; }
            if (act) {
                // f32 r7 list, strict, exact sequential replay
                if (d < kd[KE - 1]) {
                    kd[KE - 1] = d; ki[KE - 1] = g;
#pragma unroll
                    for (int t2 = KE - 1; t2 >= 1; --t2) {
                        if (kd[t2] < kd[t2 - 1]) {
                            float td = kd[t2]; kd[t2] = kd[t2 - 1]; kd[t2 - 1] = td;
                            int   ti = ki[t2]; ki[t2] = ki[t2 - 1]; ki[t2 - 1] = ti;
                        }
                    }
                }
                // f64 exact list (identical chain to the tile version)
                const float* pg = bx + (size_t)g * 3u;
                float x = pg[0], y = pg[1], z = pg[2];
                double xd = (double)x, yd = (double)y, zd = (double)z;
                double tq64  = xd * xd + yd * yd + zd * zd;
                double dot64 = xd * qxd + yd * qyd + zd * qzd;
                double d64   = qsq64 + tq64 - 2.0 * dot64;
                if (d64 < kd64[KK - 1]) {
                    kd64[KK - 1] = d64; ki64[KK - 1] = g;
#pragma unroll
                    for (int t2 = KK - 1; t2 >= 1; --t2) {
                        if (kd64[t2] < kd64[t2 - 1]) {
                            double td = kd64[t2]; kd64[t2] = kd64[t2 - 1]; kd64[t2 - 1] = td;
                            int    ti = ki64[t2]; ki64[t2] = ki64[t2 - 1]; ki64[t2 - 1] = ti;
                        }
                    }
                }
            }
        }
        cnt  = 0;
        taum = kd[KE - 1] + MARGIN;
    };

    for (int g0 = 0; g0 < NN; g0 += 4) {
#pragma unroll
        for (int u = 0; u < 4; ++u) {
            int g = g0 + u;
            float x = bx[g * 3 + 0];
            float y = bx[g * 3 + 1];
            float z = bx[g * 3 + 2];
            float tq  = addrn(addrn(mulrn(x, x), mulrn(y, y)), mulrn(z, z));
            float dot = fmaf(z, qz, fmaf(y, qy, mulrn(x, qx)));
            float d   = subrn(addrn(qsq, tq), mulrn(2.0f, dot));
            if (d < taum) { sd[cnt][tid] = d; sg[cnt][tid] = g; ++cnt; }
        }
        if (__any(cnt > CAP - 4)) drain();
    }
    drain();

    bool agree = true;
#pragma unroll
    for (int t = 0; t < KK; ++t) agree = agree && (ki[t] == ki64[t]);

    bool hastie = false;
#pragma unroll
    for (int t = 1; t < KE; ++t) hastie = hastie || (kd[t] == kd[t - 1]);

    const bool use_f32 = agree || hastie;
    int kf[KK];
#pragma unroll
    for (int t = 0; t < KK; ++t) kf[t] = use_f32 ? ki[t] : ki64[t];

    // plane features over neighbors k=1..15
    float pl[PP];
#pragma unroll
    for (int p = 0; p < PP; ++p) pl[p] = -3.0e38f;

    for (int k = 1; k < KK; ++k) {
        int g = kf[k];
        float rx = bx[g * 3 + 0] - qx;
        float ry = bx[g * 3 + 1] - qy;
        float rz = bx[g * 3 + 2] - qz;
        float nrm  = sqrtf(rx * rx + ry * ry + rz * rz) + 1e-8f;
        float invn = 1.0f / nrm;
        for (int p = 0; p < PP; ++p) {
            float t = rx * wpx[p] + ry * wpy[p] + rz * wpz[p];
            float a = t * invn;
            float v = nrm * a * fabsf(a);
            pl[p] = fmaxf(pl[p], v);
        }
    }

    // shapes: x = pl . w_shapes[q,:], BN, ReLU -> out[b*QQ*SS + q*SS + s]
    for (int q = 0; q < QQ; ++q) {
        float acc = 0.0f;
        for (int p = 0; p < PP; ++p) acc = fmaf(pl[p], wsh[q * PP + p], acc);
        float y2 = (acc - bmn[q]) * bsc[q] + bbt[q];
        y2 = fmaxf(y2, 0.0f);
        unsigned o = ((unsigned)b * QQ + (unsigned)q) * SS + (unsigned)s;
        out[o] = y2;
    }

    // idx output
    for (int t = 0; t < KK; ++t) {
        unsigned o = OFF_IDX + ((unsigned)b * SS + (unsigned)s) * (unsigned)KK + (unsigned)t;
        out[o] = (float)kf[t];
    }
}

extern "C" void kernel_launch(void* const* d_in, const int* in_sizes, int n_in,
                              void* d_out, int out_size, void* d_ws, size_t ws_size,
                              hipStream_t stream)
{
    const float* xyz      = (const float*)d_in[0];
    const float* w_planes = (const float*)d_in[1];
    const float* w_shapes = (const float*)d_in[2];
    const float* bn_gamma = (const float*)d_in[3];
    const float* bn_beta  = (const float*)d_in[4];
    const float* bn_mean  = (const float*)d_in[5];
    const float* bn_var   = (const float*)d_in[6];

    float* out = (float*)d_out;
    float* ws  = (float*)d_ws;

    const unsigned ws_floats = (unsigned)(ws_size / 4);
    const int use_ws = (ws_size >= (size_t)BB * SS * 3 * 4) ? 1 : 0;

    hipLaunchKernelGGL(fps_kernel, dim3(BB), dim3(FTH), 0, stream,
                       xyz, out, ws, ws_floats);

    hipLaunchKernelGGL(knn_shape_kernel, dim3(BB * NBLK), dim3(KTH), 0, stream,
                       xyz, ws, use_ws, ws_floats,
                       w_planes, w_shapes,
                       bn_gamma, bn_beta, bn_mean, bn_var,
                       out);
}

// Round 3
// 10669.724 us; speedup vs baseline: 1.1943x; 1.1943x over previous
//
#include <hip/hip_runtime.h>

#define BB 4
#define NN 16384
#define SS 4096
#define KK 16
#define KE 17                 // extended f32 list to expose boundary ties
#define PP 64
#define QQ 128

// flat FLOAT32 element offsets in d_out (return order: shapes, xyz_new, idx)
#define OFF_XYZNEW 2097152u   // 4*128*4096
#define OFF_IDX    2146304u   // + 4*4096*3
#define OUT_ELEMS  2408448u   // + 4*4096*16

// FPS: 512 threads (8 waves), forced 2 waves/EU -> 256-VGPR budget.
#define FTH 512
#define FPT (NN / FTH)        // 32
#define NWAVE (FTH / 64)      // 8

// KNN: 64 threads = 1 wave per block, 256 blocks -> all 256 CUs.
#define KTH 64
#define NBLK (SS / KTH)       // 64 blocks per batch
#define CAP 32                // per-lane LDS stack capacity
#define UU  16                // candidates per drain-check batch
#define MARGIN 1e-3f          // >> worst-case |d32-d64| (~4e-5): f64 coverage proof

__device__ __forceinline__ float mulrn(float a, float b) { return __fmul_rn(a, b); }
__device__ __forceinline__ float addrn(float a, float b) { return __fadd_rn(a, b); }
__device__ __forceinline__ float subrn(float a, float b) { return __fsub_rn(a, b); }

// ---------------------------------------------------------------------------
// Kernel 1: farthest point sampling, 1 block per batch.
// v4: amdgpu_waves_per_eu(2,2) forces the occupancy the compiler's heuristic
// refused (r1/r2 counters: VGPR_Count=84 < 128 array floats -> coords were
// re-streamed from L1/L2 every iteration, ~196KB/CU/iter). With min=max=2
// waves/EU the allocator gets the full 256-VGPR budget and px/py/pz/dist
// (128 floats) become register-resident. Inner loop reverted to (v,g)-only
// selection (round-2's payload cndmasks cost +96 VALU/thread/iter).
// Selection key strictly (v desc, g asc) everywhere -> sequence identical
// to the verified round-1 kernel.
// ---------------------------------------------------------------------------
__global__ __launch_bounds__(FTH)
__attribute__((amdgpu_waves_per_eu(2, 2)))
void fps_kernel(
    const float* __restrict__ xyz,
    float* __restrict__ out,
    float* __restrict__ ws, unsigned ws_floats)
{
    const int b   = blockIdx.x;
    const int tid = threadIdx.x;
    const float* base = xyz + (size_t)b * NN * 3;

    float px[FPT], py[FPT], pz[FPT], dist[FPT];
#pragma unroll
    for (int j = 0; j < FPT; ++j) {
        int g = tid + FTH * j;
        px[j] = base[g * 3 + 0];
        py[j] = base[g * 3 + 1];
        pz[j] = base[g * 3 + 2];
        dist[j] = 1e10f;
        // pin to VGPRs: value becomes opaque -> no remat-from-global
        asm volatile("" : "+v"(px[j]));
        asm volatile("" : "+v"(py[j]));
        asm volatile("" : "+v"(pz[j]));
    }

    __shared__ float wv[2][NWAVE];
    __shared__ int   wg[2][NWAVE];

    // selection 0 is index 0
    float lx = base[0], ly = base[1], lz = base[2];
    if (tid == 0) {
        unsigned o = OFF_XYZNEW + (unsigned)b * SS * 3u;
        out[o + 0] = lx; out[o + 1] = ly; out[o + 2] = lz;
        unsigned w = (unsigned)b * SS * 3u;
        if (w + 2u < ws_floats) { ws[w] = lx; ws[w + 1] = ly; ws[w + 2] = lz; }
    }

    const int lane = tid & 63;
    const int wave = tid >> 6;
    int p = 0;

    for (int s = 1; s < SS; ++s) {
        float bestv = -1.0f;
        int   bestg = 0;
#pragma unroll
        for (int j = 0; j < FPT; ++j) {
            float dx = subrn(px[j], lx);
            float dy = subrn(py[j], ly);
            float dz = subrn(pz[j], lz);
            float d  = addrn(addrn(mulrn(dx, dx), mulrn(dy, dy)), mulrn(dz, dz));
            float nd = fminf(dist[j], d);
            dist[j] = nd;
            if (nd > bestv) { bestv = nd; bestg = tid + FTH * j; }
        }
        for (int off = 32; off >= 1; off >>= 1) {
            float ov = __shfl_down(bestv, off);
            int   og = __shfl_down(bestg, off);
            if (ov > bestv || (ov == bestv && og < bestg)) { bestv = ov; bestg = og; }
        }
        if (lane == 0) { wv[p][wave] = bestv; wg[p][wave] = bestg; }
        __syncthreads();
        // single barrier: buffer p reads below are ordered before any write to
        // buffer p^1 (next iter) by this barrier; buffer p is only rewritten
        // two iterations later, after the next barrier.

        float bv = wv[p][0]; int bg = wg[p][0];
#pragma unroll
        for (int w = 1; w < NWAVE; ++w) {
            float v = wv[p][w]; int g = wg[p][w];
            if (v > bv || (v == bv && g < bg)) { bv = v; bg = g; }
        }

        // bg is block-uniform: force SGPR so the winner reload is a scalar load
        int bgu = __builtin_amdgcn_readfirstlane(bg);
        lx = base[bgu * 3 + 0];
        ly = base[bgu * 3 + 1];
        lz = base[bgu * 3 + 2];

        if (tid == 0) {
            unsigned o = OFF_XYZNEW + ((unsigned)b * SS + (unsigned)s) * 3u;
            out[o + 0] = lx; out[o + 1] = ly; out[o + 2] = lz;
            unsigned w = ((unsigned)b * SS + (unsigned)s) * 3u;
            if (w + 2u < ws_floats) { ws[w] = lx; ws[w + 1] = ly; ws[w + 2] = lz; }
        }
        p ^= 1;
    }
}

// ---------------------------------------------------------------------------
// Kernel 2 (v4): push/drain top-k, batched candidate loop.
// r2 counters: ~5% VALU duty -> latency-bound; the per-4-candidate drain
// check was a scheduling fence between load groups. Now: load 16 points as
// 12 float4 up front, evaluate all 16, drain-check once per 16.
// CAP safety: at a passing check cnt <= CAP-UU = 16; +16 pushes <= 32 = CAP.
// Lists are bit-identical (same distances, same scan order, same drains'
// sequential replay semantics). Emit rule, planes, shapes: unchanged.
// ---------------------------------------------------------------------------
__global__ __launch_bounds__(KTH) void knn_shape_kernel(
    const float* __restrict__ xyz,
    const float* __restrict__ ws, int use_ws, unsigned ws_floats,
    const float* __restrict__ w_planes, const float* __restrict__ w_shapes,
    const float* __restrict__ bn_gamma, const float* __restrict__ bn_beta,
    const float* __restrict__ bn_mean, const float* __restrict__ bn_var,
    float* __restrict__ out)
{
    __shared__ float sd[CAP][KTH];   // [cnt][lane]: bank = lane%32, conflict-free
    __shared__ int   sg[CAP][KTH];
    __shared__ float wpx[PP], wpy[PP], wpz[PP];
    __shared__ float wsh[QQ * PP];
    __shared__ float bsc[QQ], bmn[QQ], bbt[QQ];

    const int tid = threadIdx.x;
    const int blk = blockIdx.x;
    const int b   = blk / NBLK;
    const int s   = (blk % NBLK) * KTH + tid;   // [0, 4096)

    for (int i = tid; i < PP; i += KTH) {
        wpx[i] = w_planes[i * 3 + 0];
        wpy[i] = w_planes[i * 3 + 1];
        wpz[i] = w_planes[i * 3 + 2];
    }
    for (int i = tid; i < QQ * PP; i += KTH) wsh[i] = w_shapes[i];
    for (int i = tid; i < QQ; i += KTH) {
        bsc[i] = bn_gamma[i] / sqrtf(bn_var[i] + 1e-5f);
        bmn[i] = bn_mean[i];
        bbt[i] = bn_beta[i];
    }
    __syncthreads();

    const float* bx = xyz + (size_t)b * NN * 3;

    float qx, qy, qz;
    {
        unsigned w = ((unsigned)b * SS + (unsigned)s) * 3u;
        if (use_ws && w + 2u < ws_floats) {
            qx = ws[w]; qy = ws[w + 1]; qz = ws[w + 2];
        } else {
            unsigned o = OFF_XYZNEW + w;
            qx = out[o + 0]; qy = out[o + 1]; qz = out[o + 2];
        }
    }
    const float  qsq   = addrn(addrn(mulrn(qx, qx), mulrn(qy, qy)), mulrn(qz, qz));
    const double qxd = (double)qx, qyd = (double)qy, qzd = (double)qz;
    const double qsq64 = qxd * qxd + qyd * qyd + qzd * qzd;

    float  kd[KE];   int ki[KE];
    double kd64[KK]; int ki64[KK];
#pragma unroll
    for (int t = 0; t < KE; ++t) { kd[t] = 3.0e38f; ki[t] = 0; }
#pragma unroll
    for (int t = 0; t < KK; ++t) { kd64[t] = 1.0e300; ki64[t] = 0; }

    int   cnt  = 0;
    float taum = 3.0e38f;

    auto drain = [&]() {
        for (int t = 0; t < CAP; ++t) {
            if (!__any(t < cnt)) break;
            const bool act = t < cnt;
            float d = 0.0f; int g = 0;
            if (act) { d = sd[t][tid]; g = sg[t][tid]; }
            if (act) {
                // f32 r7 list, strict, exact sequential replay
                if (d < kd[KE - 1]) {
                    kd[KE - 1] = d; ki[KE - 1] = g;
#pragma unroll
                    for (int t2 = KE - 1; t2 >= 1; --t2) {
                        if (kd[t2] < kd[t2 - 1]) {
                            float td = kd[t2]; kd[t2] = kd[t2 - 1]; kd[t2 - 1] = td;
                            int   ti = ki[t2]; ki[t2] = ki[t2 - 1]; ki[t2 - 1] = ti;
                        }
                    }
                }
                // f64 exact list (identical chain to the tile version)
                const float* pg = bx + (size_t)g * 3u;
                float x = pg[0], y = pg[1], z = pg[2];
                double xd = (double)x, yd = (double)y, zd = (double)z;
                double tq64  = xd * xd + yd * yd + zd * zd;
                double dot64 = xd * qxd + yd * qyd + zd * qzd;
                double d64   = qsq64 + tq64 - 2.0 * dot64;
                if (d64 < kd64[KK - 1]) {
                    kd64[KK - 1] = d64; ki64[KK - 1] = g;
#pragma unroll
                    for (int t2 = KK - 1; t2 >= 1; --t2) {
                        if (kd64[t2] < kd64[t2 - 1]) {
                            double td = kd64[t2]; kd64[t2] = kd64[t2 - 1]; kd64[t2 - 1] = td;
                            int    ti = ki64[t2]; ki64[t2] = ki64[t2 - 1]; ki64[t2 - 1] = ti;
                        }
                    }
                }
            }
        }
        cnt  = 0;
        taum = kd[KE - 1] + MARGIN;
    };

    for (int g0 = 0; g0 < NN; g0 += UU) {
        // 16 points = 48 floats = 12 float4, issued as one load batch
        float4 c4[12];
        const float4* p4 = reinterpret_cast<const float4*>(bx + (size_t)g0 * 3u);
#pragma unroll
        for (int i = 0; i < 12; ++i) c4[i] = p4[i];
        const float* cf = reinterpret_cast<const float*>(c4);
#pragma unroll
        for (int u = 0; u < UU; ++u) {
            int g = g0 + u;
            float x = cf[u * 3 + 0];
            float y = cf[u * 3 + 1];
            float z = cf[u * 3 + 2];
            float tq  = addrn(addrn(mulrn(x, x), mulrn(y, y)), mulrn(z, z));
            float dot = fmaf(z, qz, fmaf(y, qy, mulrn(x, qx)));
            float d   = subrn(addrn(qsq, tq), mulrn(2.0f, dot));
            if (d < taum) { sd[cnt][tid] = d; sg[cnt][tid] = g; ++cnt; }
        }
        if (__any(cnt > CAP - UU)) drain();
    }
    drain();

    bool agree = true;
#pragma unroll
    for (int t = 0; t < KK; ++t) agree = agree && (ki[t] == ki64[t]);

    bool hastie = false;
#pragma unroll
    for (int t = 1; t < KE; ++t) hastie = hastie || (kd[t] == kd[t - 1]);

    const bool use_f32 = agree || hastie;
    int kf[KK];
#pragma unroll
    for (int t = 0; t < KK; ++t) kf[t] = use_f32 ? ki[t] : ki64[t];

    // plane features over neighbors k=1..15
    float pl[PP];
#pragma unroll
    for (int p = 0; p < PP; ++p) pl[p] = -3.0e38f;

    for (int k = 1; k < KK; ++k) {
        int g = kf[k];
        float rx = bx[g * 3 + 0] - qx;
        float ry = bx[g * 3 + 1] - qy;
        float rz = bx[g * 3 + 2] - qz;
        float nrm  = sqrtf(rx * rx + ry * ry + rz * rz) + 1e-8f;
        float invn = 1.0f / nrm;
        for (int p = 0; p < PP; ++p) {
            float t = rx * wpx[p] + ry * wpy[p] + rz * wpz[p];
            float a = t * invn;
            float v = nrm * a * fabsf(a);
            pl[p] = fmaxf(pl[p], v);
        }
    }

    // shapes: x = pl . w_shapes[q,:], BN, ReLU -> out[b*QQ*SS + q*SS + s]
    for (int q = 0; q < QQ; ++q) {
        float acc = 0.0f;
        for (int p = 0; p < PP; ++p) acc = fmaf(pl[p], wsh[q * PP + p], acc);
        float y2 = (acc - bmn[q]) * bsc[q] + bbt[q];
        y2 = fmaxf(y2, 0.0f);
        unsigned o = ((unsigned)b * QQ + (unsigned)q) * SS + (unsigned)s;
        out[o] = y2;
    }

    // idx output
    for (int t = 0; t < KK; ++t) {
        unsigned o = OFF_IDX + ((unsigned)b * SS + (unsigned)s) * (unsigned)KK + (unsigned)t;
        out[o] = (float)kf[t];
    }
}

extern "C" void kernel_launch(void* const* d_in, const int* in_sizes, int n_in,
                              void* d_out, int out_size, void* d_ws, size_t ws_size,
                              hipStream_t stream)
{
    const float* xyz      = (const float*)d_in[0];
    const float* w_planes = (const float*)d_in[1];
    const float* w_shapes = (const float*)d_in[2];
    const float* bn_gamma = (const float*)d_in[3];
    const float* bn_beta  = (const float*)d_in[4];
    const float* bn_mean  = (const float*)d_in[5];
    const float* bn_var   = (const float*)d_in[6];

    float* out = (float*)d_out;
    float* ws  = (float*)d_ws;

    const unsigned ws_floats = (unsigned)(ws_size / 4);
    const int use_ws = (ws_size >= (size_t)BB * SS * 3 * 4) ? 1 : 0;

    hipLaunchKernelGGL(fps_kernel, dim3(BB), dim3(FTH), 0, stream,
                       xyz, out, ws, ws_floats);

    hipLaunchKernelGGL(knn_shape_kernel, dim3(BB * NBLK), dim3(KTH), 0, stream,
                       xyz, ws, use_ws, ws_floats,
                       w_planes, w_shapes,
                       bn_gamma, bn_beta, bn_mean, bn_var,
                       out);
}

// Round 6
// 10467.721 us; speedup vs baseline: 1.2173x; 1.0193x over previous
//
#include <hip/hip_runtime.h>

#define BB 4
#define NN 16384
#define SS 4096
#define KK 16
#define KE 17                 // extended f32 list to expose boundary ties
#define PP 64
#define QQ 128

// flat FLOAT32 element offsets in d_out (return order: shapes, xyz_new, idx)
#define OFF_XYZNEW 2097152u   // 4*128*4096
#define OFF_IDX    2146304u   // + 4*4096*3
#define OUT_ELEMS  2408448u   // + 4*4096*16

// FPS: 512 threads (8 waves) -- exact r3 config (last passing).
#define FTH 512
#define FPT (NN / FTH)        // 32
#define PAIRS (FPT / 2)       // 16
#define NWAVE (FTH / 64)      // 8

// KNN: 64 threads = 1 wave per block, 256 blocks -> all 256 CUs.
#define KTH 64
#define NBLK (SS / KTH)       // 64 blocks per batch
#define CAP 32                // per-lane LDS stack capacity
#define UU  16                // candidates per drain-check batch
#define MARGIN 1e-3f          // >> worst-case |d32-d64| (~4e-5): f64 coverage proof

typedef float float2v __attribute__((ext_vector_type(2)));

__device__ __forceinline__ float mulrn(float a, float b) { return __fmul_rn(a, b); }
__device__ __forceinline__ float addrn(float a, float b) { return __fadd_rn(a, b); }
__device__ __forceinline__ float subrn(float a, float b) { return __fsub_rn(a, b); }

// ---------------------------------------------------------------------------
// Kernel 1: farthest point sampling, 1 block per batch.
// v7 = r3-validated structure (512 thr, waves_per_eu(2,2), pins,
// readfirstlane winner reload, single barrier/iter) with ONLY the inner
// loop packed into float2 vectors (v_pk_add/mul_f32).
// Per-element chain with fp contract(off): sub,sub,sub,mul,mul,add,mul,add
// in rn -- bit-identical to the scalar subrn/mulrn/addrn chain. fminf per
// element unchanged. Argmax visits candidates in the same ascending-g
// order with the same strict '>' (first-hit tie rule). Reduction, scan,
// winner reload, output writes: byte-identical to r3.
// NO large LDS (r4's 96KB static __shared__ was a silent launch-killer
// candidate), NO FTH/waves changes (r5 suspects).
// ---------------------------------------------------------------------------
__global__ __launch_bounds__(FTH)
__attribute__((amdgpu_waves_per_eu(2, 2)))
void fps_kernel(
    const float* __restrict__ xyz,
    float* __restrict__ out,
    float* __restrict__ ws, unsigned ws_floats)
{
    const int b   = blockIdx.x;
    const int tid = threadIdx.x;
    const float* base = xyz + (size_t)b * NN * 3;

    float2v pxx[PAIRS], pyy[PAIRS], pzz[PAIRS], pdd[PAIRS];
#pragma unroll
    for (int i = 0; i < PAIRS; ++i) {
        int g0 = tid + FTH * (2 * i);
        int g1 = tid + FTH * (2 * i + 1);
        pxx[i] = (float2v){ base[g0 * 3 + 0], base[g1 * 3 + 0] };
        pyy[i] = (float2v){ base[g0 * 3 + 1], base[g1 * 3 + 1] };
        pzz[i] = (float2v){ base[g0 * 3 + 2], base[g1 * 3 + 2] };
        pdd[i] = (float2v){ 1e10f, 1e10f };
        // pin to VGPRs: values become opaque -> no remat-from-global
        asm volatile("" : "+v"(pxx[i]));
        asm volatile("" : "+v"(pyy[i]));
        asm volatile("" : "+v"(pzz[i]));
    }

    __shared__ float wv[2][NWAVE];
    __shared__ int   wg[2][NWAVE];

    // selection 0 is index 0
    float lx = base[0], ly = base[1], lz = base[2];
    if (tid == 0) {
        unsigned o = OFF_XYZNEW + (unsigned)b * SS * 3u;
        out[o + 0] = lx; out[o + 1] = ly; out[o + 2] = lz;
        unsigned w = (unsigned)b * SS * 3u;
        if (w + 2u < ws_floats) { ws[w] = lx; ws[w + 1] = ly; ws[w + 2] = lz; }
    }

    const int lane = tid & 63;
    const int wave = tid >> 6;
    int p = 0;

    for (int s = 1; s < SS; ++s) {
#pragma clang fp contract(off)
        const float2v lx2 = (float2v){ lx, lx };
        const float2v ly2 = (float2v){ ly, ly };
        const float2v lz2 = (float2v){ lz, lz };
        float bestv = -1.0f;
        int   bestg = 0;
#pragma unroll
        for (int i = 0; i < PAIRS; ++i) {
            float2v dx = pxx[i] - lx2;                    // IEEE sub, rn, per elem
            float2v dy = pyy[i] - ly2;
            float2v dz = pzz[i] - lz2;
            float2v dd = (dx * dx + dy * dy) + dz * dz;   // contract off: mul,mul,add,mul,add
            float n0 = fminf(pdd[i].x, dd.x);
            float n1 = fminf(pdd[i].y, dd.y);
            pdd[i] = (float2v){ n0, n1 };
            // ascending-g visit order, strict '>' => identical tie behavior
            if (n0 > bestv) { bestv = n0; bestg = tid + FTH * (2 * i); }
            if (n1 > bestv) { bestv = n1; bestg = tid + FTH * (2 * i + 1); }
        }
        for (int off = 32; off >= 1; off >>= 1) {
            float ov = __shfl_down(bestv, off);
            int   og = __shfl_down(bestg, off);
            if (ov > bestv || (ov == bestv && og < bestg)) { bestv = ov; bestg = og; }
        }
        if (lane == 0) { wv[p][wave] = bestv; wg[p][wave] = bestg; }
        __syncthreads();
        // single barrier: buffer p reads below are ordered before any write to
        // buffer p^1 (next iter) by this barrier; buffer p is only rewritten
        // two iterations later, after the next barrier.

        float bv = wv[p][0]; int bg = wg[p][0];
#pragma unroll
        for (int w = 1; w < NWAVE; ++w) {
            float v = wv[p][w]; int g = wg[p][w];
            if (v > bv || (v == bv && g < bg)) { bv = v; bg = g; }
        }

        // bg is block-uniform: force SGPR so the winner reload is a scalar load
        int bgu = __builtin_amdgcn_readfirstlane(bg);
        lx = base[bgu * 3 + 0];
        ly = base[bgu * 3 + 1];
        lz = base[bgu * 3 + 2];

        if (tid == 0) {
            unsigned o = OFF_XYZNEW + ((unsigned)b * SS + (unsigned)s) * 3u;
            out[o + 0] = lx; out[o + 1] = ly; out[o + 2] = lz;
            unsigned w = ((unsigned)b * SS + (unsigned)s) * 3u;
            if (w + 2u < ws_floats) { ws[w] = lx; ws[w + 1] = ly; ws[w + 2] = lz; }
        }
        p ^= 1;
    }
}

// ---------------------------------------------------------------------------
// Kernel 2: EXACT r3 version (last passing). push/drain top-k, 16-point
// batched loads, drain check per 16 candidates. No double-buffer pipeline
// (r4/r5 suspect -- removed pending attribution).
// ---------------------------------------------------------------------------
__global__ __launch_bounds__(KTH) void knn_shape_kernel(
    const float* __restrict__ xyz,
    const float* __restrict__ ws, int use_ws, unsigned ws_floats,
    const float* __restrict__ w_planes, const float* __restrict__ w_shapes,
    const float* __restrict__ bn_gamma, const float* __restrict__ bn_beta,
    const float* __restrict__ bn_mean, const float* __restrict__ bn_var,
    float* __restrict__ out)
{
    __shared__ float sd[CAP][KTH];   // [cnt][lane]: bank = lane%32, conflict-free
    __shared__ int   sg[CAP][KTH];
    __shared__ float wpx[PP], wpy[PP], wpz[PP];
    __shared__ float wsh[QQ * PP];
    __shared__ float bsc[QQ], bmn[QQ], bbt[QQ];

    const int tid = threadIdx.x;
    const int blk = blockIdx.x;
    const int b   = blk / NBLK;
    const int s   = (blk % NBLK) * KTH + tid;   // [0, 4096)

    for (int i = tid; i < PP; i += KTH) {
        wpx[i] = w_planes[i * 3 + 0];
        wpy[i] = w_planes[i * 3 + 1];
        wpz[i] = w_planes[i * 3 + 2];
    }
    for (int i = tid; i < QQ * PP; i += KTH) wsh[i] = w_shapes[i];
    for (int i = tid; i < QQ; i += KTH) {
        bsc[i] = bn_gamma[i] / sqrtf(bn_var[i] + 1e-5f);
        bmn[i] = bn_mean[i];
        bbt[i] = bn_beta[i];
    }
    __syncthreads();

    const float* bx = xyz + (size_t)b * NN * 3;

    float qx, qy, qz;
    {
        unsigned w = ((unsigned)b * SS + (unsigned)s) * 3u;
        if (use_ws && w + 2u < ws_floats) {
            qx = ws[w]; qy = ws[w + 1]; qz = ws[w + 2];
        } else {
            unsigned o = OFF_XYZNEW + w;
            qx = out[o + 0]; qy = out[o + 1]; qz = out[o + 2];
        }
    }
    const float  qsq   = addrn(addrn(mulrn(qx, qx), mulrn(qy, qy)), mulrn(qz, qz));
    const double qxd = (double)qx, qyd = (double)qy, qzd = (double)qz;
    const double qsq64 = qxd * qxd + qyd * qyd + qzd * qzd;

    float  kd[KE];   int ki[KE];
    double kd64[KK]; int ki64[KK];
#pragma unroll
    for (int t = 0; t < KE; ++t) { kd[t] = 3.0e38f; ki[t] = 0; }
#pragma unroll
    for (int t = 0; t < KK; ++t) { kd64[t] = 1.0e300; ki64[t] = 0; }

    int   cnt  = 0;
    float taum = 3.0e38f;

    auto drain = [&]() {
        for (int t = 0; t < CAP; ++t) {
            if (!__any(t < cnt)) break;
            const bool act = t < cnt;
            float d = 0.0f; int g = 0;
            if (act) { d = sd[t][tid]; g = sg[t][tid]; }
            if (act) {
                // f32 r7 list, strict, exact sequential replay
                if (d < kd[KE - 1]) {
                    kd[KE - 1] = d; ki[KE - 1] = g;
#pragma unroll
                    for (int t2 = KE - 1; t2 >= 1; --t2) {
                        if (kd[t2] < kd[t2 - 1]) {
                            float td = kd[t2]; kd[t2] = kd[t2 - 1]; kd[t2 - 1] = td;
                            int   ti = ki[t2]; ki[t2] = ki[t2 - 1]; ki[t2 - 1] = ti;
                        }
                    }
                }
                // f64 exact list (identical chain to the tile version)
                const float* pg = bx + (size_t)g * 3u;
                float x = pg[0], y = pg[1], z = pg[2];
                double xd = (double)x, yd = (double)y, zd = (double)z;
                double tq64  = xd * xd + yd * yd + zd * zd;
                double dot64 = xd * qxd + yd * qyd + zd * qzd;
                double d64   = qsq64 + tq64 - 2.0 * dot64;
                if (d64 < kd64[KK - 1]) {
                    kd64[KK - 1] = d64; ki64[KK - 1] = g;
#pragma unroll
                    for (int t2 = KK - 1; t2 >= 1; --t2) {
                        if (kd64[t2] < kd64[t2 - 1]) {
                            double td = kd64[t2]; kd64[t2] = kd64[t2 - 1]; kd64[t2 - 1] = td;
                            int    ti = ki64[t2]; ki64[t2] = ki64[t2 - 1]; ki64[t2 - 1] = ti;
                        }
                    }
                }
            }
        }
        cnt  = 0;
        taum = kd[KE - 1] + MARGIN;
    };

    for (int g0 = 0; g0 < NN; g0 += UU) {
        // 16 points = 48 floats = 12 float4, issued as one load batch
        float4 c4[12];
        const float4* p4 = reinterpret_cast<const float4*>(bx + (size_t)g0 * 3u);
#pragma unroll
        for (int i = 0; i < 12; ++i) c4[i] = p4[i];
        const float* cf = reinterpret_cast<const float*>(c4);
#pragma unroll
        for (int u = 0; u < UU; ++u) {
            int g = g0 + u;
            float x = cf[u * 3 + 0];
            float y = cf[u * 3 + 1];
            float z = cf[u * 3 + 2];
            float tq  = addrn(addrn(mulrn(x, x), mulrn(y, y)), mulrn(z, z));
            float dot = fmaf(z, qz, fmaf(y, qy, mulrn(x, qx)));
            float d   = subrn(addrn(qsq, tq), mulrn(2.0f, dot));
            if (d < taum) { sd[cnt][tid] = d; sg[cnt][tid] = g; ++cnt; }
        }
        if (__any(cnt > CAP - UU)) drain();
    }
    drain();

    bool agree = true;
#pragma unroll
    for (int t = 0; t < KK; ++t) agree = agree && (ki[t] == ki64[t]);

    bool hastie = false;
#pragma unroll
    for (int t = 1; t < KE; ++t) hastie = hastie || (kd[t] == kd[t - 1]);

    const bool use_f32 = agree || hastie;
    int kf[KK];
#pragma unroll
    for (int t = 0; t < KK; ++t) kf[t] = use_f32 ? ki[t] : ki64[t];

    // plane features over neighbors k=1..15
    float pl[PP];
#pragma unroll
    for (int p = 0; p < PP; ++p) pl[p] = -3.0e38f;

    for (int k = 1; k < KK; ++k) {
        int g = kf[k];
        float rx = bx[g * 3 + 0] - qx;
        float ry = bx[g * 3 + 1] - qy;
        float rz = bx[g * 3 + 2] - qz;
        float nrm  = sqrtf(rx * rx + ry * ry + rz * rz) + 1e-8f;
        float invn = 1.0f / nrm;
        for (int p = 0; p < PP; ++p) {
            float t = rx * wpx[p] + ry * wpy[p] + rz * wpz[p];
            float a = t * invn;
            float v = nrm * a * fabsf(a);
            pl[p] = fmaxf(pl[p], v);
        }
    }

    // shapes: x = pl . w_shapes[q,:], BN, ReLU -> out[b*QQ*SS + q*SS + s]
    for (int q = 0; q < QQ; ++q) {
        float acc = 0.0f;
        for (int p = 0; p < PP; ++p) acc = fmaf(pl[p], wsh[q * PP + p], acc);
        float y2 = (acc - bmn[q]) * bsc[q] + bbt[q];
        y2 = fmaxf(y2, 0.0f);
        unsigned o = ((unsigned)b * QQ + (unsigned)q) * SS + (unsigned)s;
        out[o] = y2;
    }

    // idx output
    for (int t = 0; t < KK; ++t) {
        unsigned o = OFF_IDX + ((unsigned)b * SS + (unsigned)s) * (unsigned)KK + (unsigned)t;
        out[o] = (float)kf[t];
    }
}

extern "C" void kernel_launch(void* const* d_in, const int* in_sizes, int n_in,
                              void* d_out, int out_size, void* d_ws, size_t ws_size,
                              hipStream_t stream)
{
    const float* xyz      = (const float*)d_in[0];
    const float* w_planes = (const float*)d_in[1];
    const float* w_shapes = (const float*)d_in[2];
    const float* bn_gamma = (const float*)d_in[3];
    const float* bn_beta  = (const float*)d_in[4];
    const float* bn_mean  = (const float*)d_in[5];
    const float* bn_var   = (const float*)d_in[6];

    float* out = (float*)d_out;
    float* ws  = (float*)d_ws;

    const unsigned ws_floats = (unsigned)(ws_size / 4);
    const int use_ws = (ws_size >= (size_t)BB * SS * 3 * 4) ? 1 : 0;

    hipLaunchKernelGGL(fps_kernel, dim3(BB), dim3(FTH), 0, stream,
                       xyz, out, ws, ws_floats);

    hipLaunchKernelGGL(knn_shape_kernel, dim3(BB * NBLK), dim3(KTH), 0, stream,
                       xyz, ws, use_ws, ws_floats,
                       w_planes, w_shapes,
                       bn_gamma, bn_beta, bn_mean, bn_var,
                       out);
}